// Round 11
// baseline (188.709 us; speedup 1.0000x reference)
//
#include <hip/hip_runtime.h>

// BatchNeuralKB: out[b] = max_f exp(-clamp(||q_b - f||^2,0)/2)
//             = exp(-0.5 * clamp(qsq[b] - 2*max_f(dot(q_b,f) - 0.5*fsq[f]), 0))
//
// R11 FULL path: BARRIER-FREE coalesced register streaming, MX fp8 MFMA
// (16x16x128, scale=1.0). R7-R10 showed the barriered-LDS structure pins
// MFMA busy at ~21us (MX floor) with ~55% structural stall regardless of
// occupancy. Here: A (64 rows x K=384) register-resident per wave (96 VGPRs,
// plain layout); facts pre-arranged group-major (16 facts x K-slice = 2KB
// block, lane i's 32B fragment at base + i*32) so every B-fragment load is
// one fully-coalesced 1KB dwordx4 -> registers. No LDS, no __syncthreads;
// compiler emits fine-grained vmcnt(N) so next-group loads fly during MFMAs.
// 4 waves/WG share facts (4x L1 reuse), own distinct m-rows.
// A and B use identical lane->k maps (plain k-window [g*128+quad*32,+32)),
// so the MFMA's internal k-order cancels (dot invariance).
// atomicMin on uint bits of clamped d2 (>=0, order-preserving).

typedef __attribute__((ext_vector_type(4))) float f32x4;
typedef __attribute__((ext_vector_type(2))) long lx2;
typedef __attribute__((ext_vector_type(4))) long lx4;
typedef __attribute__((ext_vector_type(8))) int i32x8;
typedef __attribute__((ext_vector_type(8))) __bf16 bf16x8;        // lean path
typedef __attribute__((ext_vector_type(4))) unsigned short us4;   // lean path

#define AS1 __attribute__((address_space(1)))
#define AS3 __attribute__((address_space(3)))
__device__ __forceinline__ void gl2lds16(const void* g, void* l) {
    __builtin_amdgcn_global_load_lds((const AS1 unsigned int*)g,
                                     (AS3 unsigned int*)l, 16, 0, 0);
}

// fp32 -> fp8 e4m3fn (OCP), RNE, saturate to 448
__device__ __forceinline__ unsigned char f2e4m3(float x) {
    unsigned int u = __float_as_uint(x);
    unsigned int sign = (u >> 24) & 0x80u;
    unsigned int a = u & 0x7fffffffu;
    if (a >= 0x43e00000u) return (unsigned char)(sign | 0x7e);  // >=448 -> max
    if (a < 0x3c800000u) {                                      // < 2^-6: subnormal
        int m = (int)rintf(__uint_as_float(a) * 512.0f);        // 0..8
        return (unsigned char)(sign | (unsigned)m);
    }
    unsigned int base = a - 0x3c000000u;        // re-bias exp 127->7
    unsigned int lsb = (base >> 20) & 1u;
    unsigned int code = (base + 0x7ffffu + lsb) >> 20;  // RNE into 3-bit mantissa
    return (unsigned char)(sign | code);
}

// round-to-nearest-even fp32 -> bf16 (lean path)
__device__ __forceinline__ unsigned short f2bf(float f) {
    unsigned int u = __float_as_uint(f);
    u = (u + 0x7fffu + ((u >> 16) & 1u)) >> 16;
    return (unsigned short)u;
}

// Pack 8 consecutive fp32 -> 8B fp8 and return sum of squares contribution.
__device__ __forceinline__ unsigned long long pack8(const float* src, float& s) {
    const float4 v0 = *(const float4*)(src);
    const float4 v1 = *(const float4*)(src + 4);
    s += v0.x * v0.x + v0.y * v0.y + v0.z * v0.z + v0.w * v0.w +
         v1.x * v1.x + v1.y * v1.y + v1.z * v1.z + v1.w * v1.w;
    return (unsigned long long)f2e4m3(v0.x)        | ((unsigned long long)f2e4m3(v0.y) << 8) |
           ((unsigned long long)f2e4m3(v0.z) << 16) | ((unsigned long long)f2e4m3(v0.w) << 24) |
           ((unsigned long long)f2e4m3(v1.x) << 32) | ((unsigned long long)f2e4m3(v1.y) << 40) |
           ((unsigned long long)f2e4m3(v1.z) << 48) | ((unsigned long long)f2e4m3(v1.w) << 56);
}

// prep: init outbits; queries -> plain row-major fp8 [row][384] + qsq;
// facts -> group-major fp8 + fsq:
//   F2 offset(f,k) = (f>>4)*6144 + (k>>7)*2048 + ((k&127)>>5)*512 + (f&15)*32 + (k&31)
__global__ void prep_kernel(const float* __restrict__ rel, const float* __restrict__ a1,
                            const float* __restrict__ a2, const float* __restrict__ fr,
                            const float* __restrict__ fa1, const float* __restrict__ fa2,
                            unsigned char* __restrict__ Qf, unsigned char* __restrict__ F2,
                            float* __restrict__ qsq, float* __restrict__ fsq,
                            unsigned int* __restrict__ outbits, int B, int F) {
    const int wave = (int)(threadIdx.x >> 6);
    const int lane = threadIdx.x & 63;
    const int nq = B / 4;
    const bool isq = ((int)blockIdx.x < nq);
    const int row = isq ? ((int)blockIdx.x * 4 + wave)
                        : (((int)blockIdx.x - nq) * 4 + wave);
    if (!isq && row >= F) return;

    float s = 0.f;
    if (lane < 48) {
        const int p = lane >> 4;
        const int off = (lane & 15) * 8;
        const int k = p * 128 + off;
        const float* src = (isq ? ((p == 0) ? rel : (p == 1) ? a1 : a2)
                                : ((p == 0) ? fr : (p == 1) ? fa1 : fa2)) +
                           (size_t)row * 128 + off;
        unsigned long long pk = pack8(src, s);
        if (isq) {
            *(unsigned long long*)(Qf + (size_t)row * 384 + k) = pk;
        } else {
            const size_t dst = (size_t)(row >> 4) * 6144 + (size_t)(k >> 7) * 2048 +
                               (size_t)((k & 127) >> 5) * 512 + (size_t)(row & 15) * 32 +
                               (k & 31);
            *(unsigned long long*)(F2 + dst) = pk;
        }
    }
#pragma unroll
    for (int off = 32; off >= 1; off >>= 1) s += __shfl_xor(s, off, 64);
    if (lane == 0) (isq ? qsq : fsq)[row] = s;
    if (isq && blockIdx.x == 0)
        for (int i = threadIdx.x; i < B; i += 256) outbits[i] = 0x7f800000u;
}

// ---------- R11 FULL GEMM: barrier-free coalesced streaming ----------
union pk_t { lx4 l; i32x8 i; };

#define PF(BV, FS, IDX)                                                        \
    {                                                                          \
        const unsigned char* _p = fbase + (size_t)(IDX) * 6144;                \
        _Pragma("unroll") for (int _g = 0; _g < 3; ++_g) {                     \
            lx2 _t0 = *(const lx2*)(_p + _g * 2048);                           \
            lx2 _t1 = *(const lx2*)(_p + _g * 2048 + 16);                      \
            pk_t _q; _q.l.x = _t0.x; _q.l.y = _t0.y; _q.l.z = _t1.x; _q.l.w = _t1.y; \
            BV[_g] = _q.i;                                                     \
        }                                                                      \
        FS = fsq[(fg0 + (IDX)) * 16 + col];                                    \
    }

#define CP(BV, FS)                                                             \
    {                                                                          \
        const float _seed = -0.5f * (FS);                                      \
        f32x4 _a0 = {_seed, _seed, _seed, _seed};                              \
        f32x4 _a1 = _a0, _a2 = _a0, _a3 = _a0;                                 \
        _Pragma("unroll") for (int _g = 0; _g < 3; ++_g) {                     \
            _a0 = __builtin_amdgcn_mfma_scale_f32_16x16x128_f8f6f4(af[0][_g], BV[_g], _a0, 0, 0, 0, SCL, 0, SCL); \
            _a1 = __builtin_amdgcn_mfma_scale_f32_16x16x128_f8f6f4(af[1][_g], BV[_g], _a1, 0, 0, 0, SCL, 0, SCL); \
            _a2 = __builtin_amdgcn_mfma_scale_f32_16x16x128_f8f6f4(af[2][_g], BV[_g], _a2, 0, 0, 0, SCL, 0, SCL); \
            _a3 = __builtin_amdgcn_mfma_scale_f32_16x16x128_f8f6f4(af[3][_g], BV[_g], _a3, 0, 0, 0, SCL, 0, SCL); \
        }                                                                      \
        _Pragma("unroll") for (int _r = 0; _r < 4; ++_r) {                     \
            rowmax[0 + _r] = fmaxf(rowmax[0 + _r], _a0[_r]);                   \
            rowmax[4 + _r] = fmaxf(rowmax[4 + _r], _a1[_r]);                   \
            rowmax[8 + _r] = fmaxf(rowmax[8 + _r], _a2[_r]);                   \
            rowmax[12 + _r] = fmaxf(rowmax[12 + _r], _a3[_r]);                 \
        }                                                                      \
    }

__global__ __launch_bounds__(256, 2)
void gemm_s2_kernel(const unsigned char* __restrict__ Qf,  // [M][384] fp8 plain
                    const unsigned char* __restrict__ F2,  // group-major fp8
                    const float* __restrict__ qsq, const float* __restrict__ fsq,
                    unsigned int* __restrict__ outbits, int ngroups) {
    const int tid = threadIdx.x;
    const int lane = tid & 63;
    const int wid = tid >> 6;          // wave owns m-rows [wid*64, +64)
    const int col = lane & 15, quad = lane >> 4;
    const int m0 = blockIdx.y * 256 + wid * 64;
    const int fg0 = blockIdx.x * ngroups;
    const int SCL = 0x7f;  // e8m0 exponent 127 -> scale = 2^0 = 1.0

    // A resident: 4 i-tiles x 3 K-slices x 32B = 96 VGPRs, plain k-windows.
    i32x8 af[4][3];
#pragma unroll
    for (int i = 0; i < 4; ++i) {
        const unsigned char* base = Qf + (size_t)(m0 + i * 16 + col) * 384 + quad * 32;
#pragma unroll
        for (int g = 0; g < 3; ++g) {
            lx2 t0 = *(const lx2*)(base + g * 128);
            lx2 t1 = *(const lx2*)(base + g * 128 + 16);
            pk_t q; q.l.x = t0.x; q.l.y = t0.y; q.l.z = t1.x; q.l.w = t1.y;
            af[i][g] = q.i;
        }
    }

    float rowmax[16];
#pragma unroll
    for (int v = 0; v < 16; ++v) rowmax[v] = -3.0e38f;

    const unsigned char* fbase = F2 + (size_t)fg0 * 6144 + lane * 32;

    i32x8 bva[3], bvb[3];
    float fsa, fsb;
    PF(bva, fsa, 0);
    for (int t = 0; t < ngroups; t += 2) {
        PF(bvb, fsb, t + 1);                 // loads in flight during compute
        CP(bva, fsa);
        const int t2 = (t + 2 < ngroups) ? (t + 2) : 0;  // harmless tail re-read
        PF(bva, fsa, t2);
        CP(bvb, fsb);
    }

    // per-wave epilogue (exclusive m-rows): max over 16 cols, one atomic/row.
#pragma unroll
    for (int v = 0; v < 16; ++v) {
        float mx = rowmax[v];
#pragma unroll
        for (int off = 1; off < 16; off <<= 1) mx = fmaxf(mx, __shfl_xor(mx, off, 64));
        rowmax[v] = mx;
    }
    if (col == 0) {
#pragma unroll
        for (int i = 0; i < 4; ++i)
#pragma unroll
            for (int r = 0; r < 4; ++r) {
                const int row = m0 + i * 16 + quad * 4 + r;
                float d2 = fmaxf(fmaf(-2.0f, rowmax[i * 4 + r], qsq[row]), 0.0f);
                atomicMin(outbits + row, __float_as_uint(d2));
            }
    }
}

__global__ void finalize_kernel(float* out, int n) {
    int i = blockIdx.x * blockDim.x + threadIdx.x;
    if (i < n) {
        float d2 = __uint_as_float(((unsigned int*)out)[i]);
        out[i] = expf(-0.5f * d2);
    }
}

// ---------- fallbacks (verified in earlier rounds) ----------
__global__ void init_min_kernel(unsigned int* ob, int n) {
    int i = blockIdx.x * blockDim.x + threadIdx.x;
    if (i < n) ob[i] = 0x7f800000u;
}

__global__ void conv_rows_kernel(const float* __restrict__ p0, const float* __restrict__ p1,
                                 const float* __restrict__ p2, unsigned short* __restrict__ outb,
                                 float* __restrict__ sq, int nrows) {
    const int lane = threadIdx.x & 63;
    const int wave = threadIdx.x >> 6;
    const int row = blockIdx.x * 4 + wave;
    if (row >= nrows) return;
    float s = 0.f;
#pragma unroll
    for (int c = 0; c < 6; ++c) {
        int k = c * 64 + lane;
        const float* src = (k < 128) ? p0 : (k < 256) ? p1 : p2;
        float v = src[(size_t)row * 128 + (k & 127)];
        s += v * v;
        if (outb) outb[(size_t)row * 384 + k] = f2bf(v);
    }
#pragma unroll
    for (int off = 32; off >= 1; off >>= 1) s += __shfl_xor(s, off, 64);
    if (lane == 0) sq[row] = s;
}

__global__ __launch_bounds__(256)
void gemm_lean_kernel(const unsigned short* __restrict__ Qb,
                      const float* __restrict__ f0, const float* __restrict__ f1,
                      const float* __restrict__ f2,
                      const float* __restrict__ qsq, const float* __restrict__ fsq,
                      unsigned int* __restrict__ outbits, int K) {
    __shared__ __align__(16) unsigned short As[128 * 32];
    __shared__ __align__(16) unsigned short Bs[128 * 32];
    __shared__ float smin[128 * 2];

    const int tid = threadIdx.x;
    const int lane = tid & 63;
    const int wid = tid >> 6;
    const int wm = wid >> 1, wn = wid & 1;
    const int col = lane & 15, quad = lane >> 4;
    const int m0 = blockIdx.x * 128;
    const int n0 = blockIdx.y * 128;

    f32x4 acc[4][4];
#pragma unroll
    for (int i = 0; i < 4; ++i)
#pragma unroll
        for (int j = 0; j < 4; ++j) {
            f32x4 z = {0.f, 0.f, 0.f, 0.f};
            acc[i][j] = z;
        }

    const int nk = K >> 5;
    for (int kk = 0; kk < nk; ++kk) {
        const int k0 = kk << 5;
        __syncthreads();
#pragma unroll
        for (int it = 0; it < 2; ++it) {
            int iid = it * 256 + tid;
            int row = iid >> 2, ch = iid & 3;
            gl2lds16(Qb + ((size_t)(m0 + row) * K + k0 + ch * 8), As + (row * 32 + ch * 8));
        }
        const float* src = (k0 < 128) ? f0 : (k0 < 256) ? f1 : f2;
        const int kp = k0 & 127;
#pragma unroll
        for (int it = 0; it < 4; ++it) {
            int iid = it * 256 + tid;
            int row = iid >> 3, ch = iid & 7;
            const float4 v = *(const float4*)(src + (size_t)(n0 + row) * 128 + kp + ch * 4);
            us4 w = {f2bf(v.x), f2bf(v.y), f2bf(v.z), f2bf(v.w)};
            *(us4*)(Bs + (row * 32 + ch * 4)) = w;
        }
        __syncthreads();

        bf16x8 afr[4], bfv[4];
#pragma unroll
        for (int i = 0; i < 4; ++i)
            afr[i] = *(const bf16x8*)(As + ((wm * 64 + i * 16 + col) * 32 + quad * 8));
#pragma unroll
        for (int j = 0; j < 4; ++j)
            bfv[j] = *(const bf16x8*)(Bs + ((wn * 64 + j * 16 + col) * 32 + quad * 8));
#pragma unroll
        for (int i = 0; i < 4; ++i)
#pragma unroll
            for (int j = 0; j < 4; ++j)
                acc[i][j] = __builtin_amdgcn_mfma_f32_16x16x32_bf16(afr[i], bfv[j], acc[i][j], 0, 0, 0);
    }

    float fs[4];
#pragma unroll
    for (int j = 0; j < 4; ++j) fs[j] = fsq[n0 + wn * 64 + j * 16 + col];
#pragma unroll
    for (int i = 0; i < 4; ++i) {
#pragma unroll
        for (int r = 0; r < 4; ++r) {
            const int mrow = wm * 64 + i * 16 + quad * 4 + r;
            const float qs = qsq[m0 + mrow];
            float mn = 3.0e38f;
#pragma unroll
            for (int j = 0; j < 4; ++j) {
                float d2 = qs + fs[j] - 2.0f * acc[i][j][r];
                mn = fminf(mn, fmaxf(d2, 0.0f));
            }
#pragma unroll
            for (int off = 1; off < 16; off <<= 1) mn = fminf(mn, __shfl_xor(mn, off, 64));
            if (col == 0) smin[mrow * 2 + wn] = mn;
        }
    }
    __syncthreads();
    if (tid < 128) {
        float v = fminf(smin[tid * 2 + 0], smin[tid * 2 + 1]);
        atomicMin(outbits + m0 + tid, __float_as_uint(v));
    }
}

__global__ __launch_bounds__(256)
void tier3_kernel(const float* __restrict__ rel, const float* __restrict__ a1,
                  const float* __restrict__ a2, const float* __restrict__ fr,
                  const float* __restrict__ fa1, const float* __restrict__ fa2,
                  unsigned int* __restrict__ outbits) {
    __shared__ float qs[16][384];
    __shared__ float red[4][16];
    const int tid = threadIdx.x;
    const int qbase = blockIdx.y * 16;
    const int fbase = blockIdx.x * 2048;
    for (int i = tid; i < 16 * 384; i += 256) {
        int r = i / 384, c = i % 384;
        const float* src = (c < 128) ? rel : (c < 256) ? a1 : a2;
        qs[r][c] = src[(size_t)(qbase + r) * 128 + (c & 127)];
    }
    __syncthreads();
    float mn[16];
#pragma unroll
    for (int q = 0; q < 16; ++q) mn[q] = 3.0e38f;
    for (int fi = 0; fi < 2048; fi += 256) {
        const int f = fbase + fi + tid;
        float acc[16];
#pragma unroll
        for (int q = 0; q < 16; ++q) acc[q] = 0.f;
#pragma unroll
        for (int p = 0; p < 3; ++p) {
            const float* fptr = ((p == 0) ? fr : (p == 1) ? fa1 : fa2) + (size_t)f * 128;
            for (int k4 = 0; k4 < 32; ++k4) {
                const float4 fv = *(const float4*)(fptr + k4 * 4);
#pragma unroll
                for (int q = 0; q < 16; ++q) {
                    float d0 = fv.x - qs[q][p * 128 + k4 * 4 + 0];
                    float d1 = fv.y - qs[q][p * 128 + k4 * 4 + 1];
                    float d2 = fv.z - qs[q][p * 128 + k4 * 4 + 2];
                    float d3 = fv.w - qs[q][p * 128 + k4 * 4 + 3];
                    acc[q] += d0 * d0 + d1 * d1 + d2 * d2 + d3 * d3;
                }
            }
        }
#pragma unroll
        for (int q = 0; q < 16; ++q) mn[q] = fminf(mn[q], fmaxf(acc[q], 0.f));
    }
#pragma unroll
    for (int q = 0; q < 16; ++q) {
        float v = mn[q];
#pragma unroll
        for (int off = 32; off >= 1; off >>= 1) v = fminf(v, __shfl_xor(v, off, 64));
        if ((tid & 63) == 0) red[tid >> 6][q] = v;
    }
    __syncthreads();
    if (tid < 16) {
        float v = fminf(fminf(red[0][tid], red[1][tid]), fminf(red[2][tid], red[3][tid]));
        atomicMin(outbits + qbase + tid, __float_as_uint(v));
    }
}

extern "C" void kernel_launch(void* const* d_in, const int* in_sizes, int n_in,
                              void* d_out, int out_size, void* d_ws, size_t ws_size,
                              hipStream_t stream) {
    const float* rel = (const float*)d_in[0];
    const float* a1 = (const float*)d_in[1];
    const float* a2 = (const float*)d_in[2];
    const float* fr = (const float*)d_in[3];
    const float* fa1 = (const float*)d_in[4];
    const float* fa2 = (const float*)d_in[5];

    const int E = 128, K = 384;
    const int B = in_sizes[0] / E;   // 2048
    const int F = in_sizes[3] / E;   // 65536

    float* out = (float*)d_out;
    unsigned int* outbits = (unsigned int*)d_out;

    const size_t ff_bytes = (size_t)F * K;       // 24 MB facts fp8
    const size_t qf_bytes = (size_t)B * K;       // 768 KB queries fp8
    const size_t need_full = ff_bytes + qf_bytes + (size_t)F * 4 + (size_t)B * 4;
    const size_t qb_bytes = (size_t)B * K * 2;
    const size_t need_lean = qb_bytes + (size_t)F * 4 + (size_t)B * 4;

    const bool shapes_ok = (B % 256 == 0) && (F % 1024 == 0);
    if (ws_size >= need_full && shapes_ok) {
        unsigned char* F2 = (unsigned char*)d_ws;
        unsigned char* Qf = (unsigned char*)d_ws + ff_bytes;
        float* fsq = (float*)((char*)d_ws + ff_bytes + qf_bytes);
        float* qsq = fsq + F;
        prep_kernel<<<B / 4 + F / 4, 256, 0, stream>>>(rel, a1, a2, fr, fa1, fa2,
                                                       Qf, F2, qsq, fsq, outbits, B, F);
        // grid: x = 64 fact-splits (1024 facts = 64 groups each), y = 8 m-tiles
        // of 256 rows. 512 WGs @ 2/CU, zero barriers in the hot loop.
        gemm_s2_kernel<<<dim3(F / 1024, B / 256), 256, 0, stream>>>(
            Qf, F2, qsq, fsq, outbits, 64);
    } else if (ws_size >= need_lean && B % 128 == 0 && F % 128 == 0) {
        unsigned short* Qb = (unsigned short*)d_ws;
        float* fsq = (float*)((char*)d_ws + qb_bytes);
        float* qsq = fsq + F;
        init_min_kernel<<<(B + 255) / 256, 256, 0, stream>>>(outbits, B);
        conv_rows_kernel<<<B / 4, 256, 0, stream>>>(rel, a1, a2, Qb, qsq, B);
        conv_rows_kernel<<<F / 4, 256, 0, stream>>>(fr, fa1, fa2, nullptr, fsq, F);
        gemm_lean_kernel<<<dim3(B / 128, F / 128), 256, 0, stream>>>(
            Qb, fr, fa1, fa2, qsq, fsq, outbits, K);
    } else {
        init_min_kernel<<<(B + 255) / 256, 256, 0, stream>>>(outbits, B);
        tier3_kernel<<<dim3(F / 2048, B / 16), 256, 0, stream>>>(rel, a1, a2, fr, fa1, fa2, outbits);
    }

    finalize_kernel<<<(B + 255) / 256, 256, 0, stream>>>(out, B);
}

// Round 12
// 175.633 us; speedup vs baseline: 1.0745x; 1.0745x over previous
//
#include <hip/hip_runtime.h>

// BatchNeuralKB: out[b] = max_f exp(-clamp(||q_b - f||^2,0)/2)
//             = exp(-0.5 * clamp(qsq[b] + min_f(fsq[f] - 2*dot(q_b,f)), 0))
//
// R12 FULL path: R9's verified structure (MX fp8 16x16x128, A-register-resident,
// single-barrier double-buffered B staging) + two dependency fixes:
//  (a) fsq acc-seeds prefetched one round ahead (round's first MFMA no longer
//      waits on a fresh global load);
//  (b) depth-2 software pipeline of B-fragment ds_reads (rotating 3 reg groups,
//      step s+2's reads issued before step s's MFMAs -> ~276 cyc read->use
//      distance covers the ~120 cyc LDS latency the JIT pattern exposed).
// Layout identical to R3..R11 (k-permuted + chunk-swizzled, conflicts==0).
// atomicMin on uint bits of clamped d2 (>=0, order-preserving).

typedef __attribute__((ext_vector_type(4))) float f32x4;
typedef __attribute__((ext_vector_type(2))) long lx2;
typedef __attribute__((ext_vector_type(4))) long lx4;
typedef __attribute__((ext_vector_type(8))) int i32x8;
typedef __attribute__((ext_vector_type(8))) __bf16 bf16x8;        // lean path
typedef __attribute__((ext_vector_type(4))) unsigned short us4;   // lean path

#define AS1 __attribute__((address_space(1)))
#define AS3 __attribute__((address_space(3)))
__device__ __forceinline__ void gl2lds16(const void* g, void* l) {
    __builtin_amdgcn_global_load_lds((const AS1 unsigned int*)g,
                                     (AS3 unsigned int*)l, 16, 0, 0);
}

// fp32 -> fp8 e4m3fn (OCP), RNE, saturate to 448
__device__ __forceinline__ unsigned char f2e4m3(float x) {
    unsigned int u = __float_as_uint(x);
    unsigned int sign = (u >> 24) & 0x80u;
    unsigned int a = u & 0x7fffffffu;
    if (a >= 0x43e00000u) return (unsigned char)(sign | 0x7e);  // >=448 -> max
    if (a < 0x3c800000u) {                                      // < 2^-6: subnormal
        int m = (int)rintf(__uint_as_float(a) * 512.0f);        // 0..8
        return (unsigned char)(sign | (unsigned)m);
    }
    unsigned int base = a - 0x3c000000u;        // re-bias exp 127->7
    unsigned int lsb = (base >> 20) & 1u;
    unsigned int code = (base + 0x7ffffu + lsb) >> 20;  // RNE into 3-bit mantissa
    return (unsigned char)(sign | code);
}

// round-to-nearest-even fp32 -> bf16 (lean path)
__device__ __forceinline__ unsigned short f2bf(float f) {
    unsigned int u = __float_as_uint(f);
    u = (u + 0x7fffu + ((u >> 16) & 1u)) >> 16;
    return (unsigned short)u;
}

// Convert one concat row to permuted+swizzled fp8 and compute sum-of-squares.
// Storage pos of orig k (= g*64+s*32+quad*8+r): g*64 + (quad^((row>>1)&3))*16 + s*8 + r
__device__ __forceinline__ void conv_row_fp8(const float* __restrict__ p0,
                                             const float* __restrict__ p1,
                                             const float* __restrict__ p2,
                                             int row, unsigned char* __restrict__ outb,
                                             float* __restrict__ sq) {
    const int lane = threadIdx.x & 63;
    float s = 0.f;
    if (lane < 48) {
        const int p = lane >> 4;
        const int off = (lane & 15) * 8;
        const float* src = ((p == 0) ? p0 : (p == 1) ? p1 : p2) + (size_t)row * 128 + off;
        const float4 v0 = *(const float4*)(src);
        const float4 v1 = *(const float4*)(src + 4);
        s = v0.x * v0.x + v0.y * v0.y + v0.z * v0.z + v0.w * v0.w +
            v1.x * v1.x + v1.y * v1.y + v1.z * v1.z + v1.w * v1.w;
        const int k = p * 128 + off;
        const int g = k >> 6;
        const int ss = (k >> 5) & 1;
        const int quad = (k >> 3) & 3;
        const int cs = quad ^ ((row >> 1) & 3);
        unsigned long long pk =
            (unsigned long long)f2e4m3(v0.x)        | ((unsigned long long)f2e4m3(v0.y) << 8) |
            ((unsigned long long)f2e4m3(v0.z) << 16) | ((unsigned long long)f2e4m3(v0.w) << 24) |
            ((unsigned long long)f2e4m3(v1.x) << 32) | ((unsigned long long)f2e4m3(v1.y) << 40) |
            ((unsigned long long)f2e4m3(v1.z) << 48) | ((unsigned long long)f2e4m3(v1.w) << 56);
        *(unsigned long long*)(outb + (size_t)row * 384 + g * 64 + cs * 16 + ss * 8) = pk;
    }
#pragma unroll
    for (int off = 32; off >= 1; off >>= 1) s += __shfl_xor(s, off, 64);
    if (lane == 0) sq[row] = s;
}

// One launch: init outbits + convert queries + convert facts.
__global__ void prep_kernel(const float* __restrict__ rel, const float* __restrict__ a1,
                            const float* __restrict__ a2, const float* __restrict__ fr,
                            const float* __restrict__ fa1, const float* __restrict__ fa2,
                            unsigned char* __restrict__ Qf, unsigned char* __restrict__ Ff,
                            float* __restrict__ qsq, float* __restrict__ fsq,
                            unsigned int* __restrict__ outbits, int B, int F) {
    const int wave = (int)(threadIdx.x >> 6);
    const int nq = B / 4;
    if ((int)blockIdx.x < nq) {
        conv_row_fp8(rel, a1, a2, blockIdx.x * 4 + wave, Qf, qsq);
        if (blockIdx.x == 0)
            for (int i = threadIdx.x; i < B; i += 256) outbits[i] = 0x7f800000u;
    } else {
        const int row = ((int)blockIdx.x - nq) * 4 + wave;
        if (row < F) conv_row_fp8(fr, fa1, fa2, row, Ff, fsq);
    }
}

// Stage one 64-fact tile (24 KB, all of K) into buf. LDS layout
// [kk][g][row][ch16B]: iid*16 = kk*8192 + g*4096 + row*64 + ch*16.
__device__ __forceinline__ void stage_tile(const unsigned char* __restrict__ Ff,
                                           unsigned char* buf, int n0, int tid) {
#pragma unroll
    for (int it = 0; it < 6; ++it) {
        int iid = it * 256 + tid;
        gl2lds16(Ff + (size_t)(n0 + ((iid >> 2) & 63)) * 384 +
                     (iid >> 9) * 128 + ((iid >> 8) & 1) * 64 + (iid & 3) * 16,
                 buf + (size_t)iid * 16);
    }
}

// ---------- R12 FULL GEMM: R9 + fsq-prefetch + depth-2 B reg pipeline -------
__global__ __launch_bounds__(256, 2)
void gemm_pipe_kernel(const unsigned char* __restrict__ Qf,  // [M][384] fp8 permuted
                      const unsigned char* __restrict__ Ff,  // [N][384] fp8 permuted
                      const float* __restrict__ qsq, const float* __restrict__ fsq,
                      unsigned int* __restrict__ outbits, int ntiles) {
    __shared__ __align__(16) unsigned char Bs[2][24576];  // 2 x 24 KB

    const int tid = threadIdx.x;
    const int lane = tid & 63;
    const int wid = tid >> 6;          // wave owns m-rows [wid*64, wid*64+64)
    const int col = lane & 15, quad = lane >> 4;
    const int swc = ((col >> 1) & 3);
    const int cp = (quad ^ swc) * 16;  // swizzled chunk byte offset
    const int m0 = blockIdx.y * 256;
    const int nbase = blockIdx.x * (ntiles * 64);
    const int SCL = 0x7f;  // e8m0 exponent 127 -> scale = 2^0 = 1.0

    union pk_t { lx4 l; i32x8 i; };

    // A operand fully resident: 4 i-tiles x 3 K-slices x 32B = 96 VGPRs.
    i32x8 af8[4][3];
#pragma unroll
    for (int i = 0; i < 4; ++i) {
        const unsigned char* base = Qf + (size_t)(m0 + wid * 64 + i * 16 + col) * 384;
#pragma unroll
        for (int kk = 0; kk < 3; ++kk) {
            lx2 t0 = *(const lx2*)(base + kk * 128 + cp);
            lx2 t1 = *(const lx2*)(base + kk * 128 + 64 + cp);
            pk_t p; p.l.x = t0.x; p.l.y = t0.y; p.l.z = t1.x; p.l.w = t1.y;
            af8[i][kk] = p.i;
        }
    }

    float rowmin[16];
#pragma unroll
    for (int v = 0; v < 16; ++v) rowmin[v] = 3.0e38f;

    // fsq seeds prefetched one round ahead (registers; no global dep at round start)
    float fs_cur[4], fs_nxt[4];
#pragma unroll
    for (int j = 0; j < 4; ++j) fs_cur[j] = fsq[nbase + j * 16 + col];

    stage_tile(Ff, Bs[0], nbase, tid);  // prologue prefetch
    for (int t = 0; t < ntiles; ++t) {
        __syncthreads();  // drains tile t's staging (issued one full round ago)
        if (t + 1 < ntiles) {
            stage_tile(Ff, Bs[(t + 1) & 1], nbase + (t + 1) * 64, tid);
#pragma unroll
            for (int j = 0; j < 4; ++j)
                fs_nxt[j] = fsq[nbase + (t + 1) * 64 + j * 16 + col];
        }
        const unsigned char* bb = Bs[t & 1];

        // acc seeded with -0.5*fsq (prefetched) => min_f(fsq-2dot) = -2*max over j
        f32x4 acc[4][4];
#pragma unroll
        for (int j = 0; j < 4; ++j) {
            float seed = -0.5f * fs_cur[j];
            f32x4 z = {seed, seed, seed, seed};
#pragma unroll
            for (int i = 0; i < 4; ++i) acc[i][j] = z;
        }

        // 12 steps s=(j,kk), depth-2 software pipeline of B-fragment reads:
        // step s+2's ds_reads issued before step s's 4 MFMAs.
        i32x8 bv[3];
#define LOADB(S, DST)                                                          \
        {                                                                      \
            const int _j = (S) / 3, _kk = (S) % 3;                             \
            const unsigned char* pb = bb + _kk * 8192 + (_j * 16 + col) * 64 + cp; \
            lx2 t0 = *(const lx2*)(pb);                                        \
            lx2 t1 = *(const lx2*)(pb + 4096);                                 \
            pk_t p; p.l.x = t0.x; p.l.y = t0.y; p.l.z = t1.x; p.l.w = t1.y;    \
            DST = p.i;                                                         \
        }
#define MFMAS(S, SRC)                                                          \
        {                                                                      \
            const int _j = (S) / 3, _kk = (S) % 3;                             \
            _Pragma("unroll") for (int _i = 0; _i < 4; ++_i)                   \
                acc[_i][_j] = __builtin_amdgcn_mfma_scale_f32_16x16x128_f8f6f4(\
                    af8[_i][_kk], SRC, acc[_i][_j], 0, 0, 0, SCL, 0, SCL);     \
        }
        LOADB(0, bv[0]);
        LOADB(1, bv[1]);
#pragma unroll
        for (int s = 0; s < 12; ++s) {
            if (s + 2 < 12) LOADB(s + 2, bv[(s + 2) % 3]);
            MFMAS(s, bv[s % 3]);
        }
#undef LOADB
#undef MFMAS

        // fold tile into register row minima
#pragma unroll
        for (int i = 0; i < 4; ++i)
#pragma unroll
            for (int r = 0; r < 4; ++r) {
                float mn = rowmin[i * 4 + r];
#pragma unroll
                for (int j = 0; j < 4; ++j)
                    mn = fminf(mn, -2.0f * acc[i][j][r]);
                rowmin[i * 4 + r] = mn;
            }
#pragma unroll
        for (int j = 0; j < 4; ++j) fs_cur[j] = fs_nxt[j];
    }

    // per-wave epilogue (each wave owns exclusive m-rows): min over 16 cols,
    // then one atomic per row.
#pragma unroll
    for (int v = 0; v < 16; ++v) {
        float mn = rowmin[v];
#pragma unroll
        for (int off = 1; off < 16; off <<= 1) mn = fminf(mn, __shfl_xor(mn, off, 64));
        rowmin[v] = mn;
    }
    if (col == 0) {
#pragma unroll
        for (int i = 0; i < 4; ++i)
#pragma unroll
            for (int r = 0; r < 4; ++r) {
                const int row = m0 + wid * 64 + i * 16 + quad * 4 + r;
                float d2 = fmaxf(qsq[row] + rowmin[i * 4 + r], 0.0f);
                atomicMin(outbits + row, __float_as_uint(d2));
            }
    }
}

__global__ void finalize_kernel(float* out, int n) {
    int i = blockIdx.x * blockDim.x + threadIdx.x;
    if (i < n) {
        float d2 = __uint_as_float(((unsigned int*)out)[i]);
        out[i] = expf(-0.5f * d2);
    }
}

// ---------- fallbacks (verified in earlier rounds) ----------
__global__ void init_min_kernel(unsigned int* ob, int n) {
    int i = blockIdx.x * blockDim.x + threadIdx.x;
    if (i < n) ob[i] = 0x7f800000u;
}

__global__ void conv_rows_kernel(const float* __restrict__ p0, const float* __restrict__ p1,
                                 const float* __restrict__ p2, unsigned short* __restrict__ outb,
                                 float* __restrict__ sq, int nrows) {
    const int lane = threadIdx.x & 63;
    const int wave = threadIdx.x >> 6;
    const int row = blockIdx.x * 4 + wave;
    if (row >= nrows) return;
    float s = 0.f;
#pragma unroll
    for (int c = 0; c < 6; ++c) {
        int k = c * 64 + lane;
        const float* src = (k < 128) ? p0 : (k < 256) ? p1 : p2;
        float v = src[(size_t)row * 128 + (k & 127)];
        s += v * v;
        if (outb) outb[(size_t)row * 384 + k] = f2bf(v);
    }
#pragma unroll
    for (int off = 32; off >= 1; off >>= 1) s += __shfl_xor(s, off, 64);
    if (lane == 0) sq[row] = s;
}

__global__ __launch_bounds__(256)
void gemm_lean_kernel(const unsigned short* __restrict__ Qb,
                      const float* __restrict__ f0, const float* __restrict__ f1,
                      const float* __restrict__ f2,
                      const float* __restrict__ qsq, const float* __restrict__ fsq,
                      unsigned int* __restrict__ outbits, int K) {
    __shared__ __align__(16) unsigned short As[128 * 32];
    __shared__ __align__(16) unsigned short Bs[128 * 32];
    __shared__ float smin[128 * 2];

    const int tid = threadIdx.x;
    const int lane = tid & 63;
    const int wid = tid >> 6;
    const int wm = wid >> 1, wn = wid & 1;
    const int col = lane & 15, quad = lane >> 4;
    const int m0 = blockIdx.x * 128;
    const int n0 = blockIdx.y * 128;

    f32x4 acc[4][4];
#pragma unroll
    for (int i = 0; i < 4; ++i)
#pragma unroll
        for (int j = 0; j < 4; ++j) {
            f32x4 z = {0.f, 0.f, 0.f, 0.f};
            acc[i][j] = z;
        }

    const int nk = K >> 5;
    for (int kk = 0; kk < nk; ++kk) {
        const int k0 = kk << 5;
        __syncthreads();
#pragma unroll
        for (int it = 0; it < 2; ++it) {
            int iid = it * 256 + tid;
            int row = iid >> 2, ch = iid & 3;
            gl2lds16(Qb + ((size_t)(m0 + row) * K + k0 + ch * 8), As + (row * 32 + ch * 8));
        }
        const float* src = (k0 < 128) ? f0 : (k0 < 256) ? f1 : f2;
        const int kp = k0 & 127;
#pragma unroll
        for (int it = 0; it < 4; ++it) {
            int iid = it * 256 + tid;
            int row = iid >> 3, ch = iid & 7;
            const float4 v = *(const float4*)(src + (size_t)(n0 + row) * 128 + kp + ch * 4);
            us4 w = {f2bf(v.x), f2bf(v.y), f2bf(v.z), f2bf(v.w)};
            *(us4*)(Bs + (row * 32 + ch * 4)) = w;
        }
        __syncthreads();

        bf16x8 afr[4], bfv[4];
#pragma unroll
        for (int i = 0; i < 4; ++i)
            afr[i] = *(const bf16x8*)(As + ((wm * 64 + i * 16 + col) * 32 + quad * 8));
#pragma unroll
        for (int j = 0; j < 4; ++j)
            bfv[j] = *(const bf16x8*)(Bs + ((wn * 64 + j * 16 + col) * 32 + quad * 8));
#pragma unroll
        for (int i = 0; i < 4; ++i)
#pragma unroll
            for (int j = 0; j < 4; ++j)
                acc[i][j] = __builtin_amdgcn_mfma_f32_16x16x32_bf16(afr[i], bfv[j], acc[i][j], 0, 0, 0);
    }

    float fs[4];
#pragma unroll
    for (int j = 0; j < 4; ++j) fs[j] = fsq[n0 + wn * 64 + j * 16 + col];
#pragma unroll
    for (int i = 0; i < 4; ++i) {
#pragma unroll
        for (int r = 0; r < 4; ++r) {
            const int mrow = wm * 64 + i * 16 + quad * 4 + r;
            const float qs = qsq[m0 + mrow];
            float mn = 3.0e38f;
#pragma unroll
            for (int j = 0; j < 4; ++j) {
                float d2 = qs + fs[j] - 2.0f * acc[i][j][r];
                mn = fminf(mn, fmaxf(d2, 0.0f));
            }
#pragma unroll
            for (int off = 1; off < 16; off <<= 1) mn = fminf(mn, __shfl_xor(mn, off, 64));
            if (col == 0) smin[mrow * 2 + wn] = mn;
        }
    }
    __syncthreads();
    if (tid < 128) {
        float v = fminf(smin[tid * 2 + 0], smin[tid * 2 + 1]);
        atomicMin(outbits + m0 + tid, __float_as_uint(v));
    }
}

__global__ __launch_bounds__(256)
void tier3_kernel(const float* __restrict__ rel, const float* __restrict__ a1,
                  const float* __restrict__ a2, const float* __restrict__ fr,
                  const float* __restrict__ fa1, const float* __restrict__ fa2,
                  unsigned int* __restrict__ outbits) {
    __shared__ float qs[16][384];
    __shared__ float red[4][16];
    const int tid = threadIdx.x;
    const int qbase = blockIdx.y * 16;
    const int fbase = blockIdx.x * 2048;
    for (int i = tid; i < 16 * 384; i += 256) {
        int r = i / 384, c = i % 384;
        const float* src = (c < 128) ? rel : (c < 256) ? a1 : a2;
        qs[r][c] = src[(size_t)(qbase + r) * 128 + (c & 127)];
    }
    __syncthreads();
    float mn[16];
#pragma unroll
    for (int q = 0; q < 16; ++q) mn[q] = 3.0e38f;
    for (int fi = 0; fi < 2048; fi += 256) {
        const int f = fbase + fi + tid;
        float acc[16];
#pragma unroll
        for (int q = 0; q < 16; ++q) acc[q] = 0.f;
#pragma unroll
        for (int p = 0; p < 3; ++p) {
            const float* fptr = ((p == 0) ? fr : (p == 1) ? fa1 : fa2) + (size_t)f * 128;
            for (int k4 = 0; k4 < 32; ++k4) {
                const float4 fv = *(const float4*)(fptr + k4 * 4);
#pragma unroll
                for (int q = 0; q < 16; ++q) {
                    float d0 = fv.x - qs[q][p * 128 + k4 * 4 + 0];
                    float d1 = fv.y - qs[q][p * 128 + k4 * 4 + 1];
                    float d2 = fv.z - qs[q][p * 128 + k4 * 4 + 2];
                    float d3 = fv.w - qs[q][p * 128 + k4 * 4 + 3];
                    acc[q] += d0 * d0 + d1 * d1 + d2 * d2 + d3 * d3;
                }
            }
        }
#pragma unroll
        for (int q = 0; q < 16; ++q) mn[q] = fminf(mn[q], fmaxf(acc[q], 0.f));
    }
#pragma unroll
    for (int q = 0; q < 16; ++q) {
        float v = mn[q];
#pragma unroll
        for (int off = 32; off >= 1; off >>= 1) v = fminf(v, __shfl_xor(v, off, 64));
        if ((tid & 63) == 0) red[tid >> 6][q] = v;
    }
    __syncthreads();
    if (tid < 16) {
        float v = fminf(fminf(red[0][tid], red[1][tid]), fminf(red[2][tid], red[3][tid]));
        atomicMin(outbits + qbase + tid, __float_as_uint(v));
    }
}

extern "C" void kernel_launch(void* const* d_in, const int* in_sizes, int n_in,
                              void* d_out, int out_size, void* d_ws, size_t ws_size,
                              hipStream_t stream) {
    const float* rel = (const float*)d_in[0];
    const float* a1 = (const float*)d_in[1];
    const float* a2 = (const float*)d_in[2];
    const float* fr = (const float*)d_in[3];
    const float* fa1 = (const float*)d_in[4];
    const float* fa2 = (const float*)d_in[5];

    const int E = 128, K = 384;
    const int B = in_sizes[0] / E;   // 2048
    const int F = in_sizes[3] / E;   // 65536

    float* out = (float*)d_out;
    unsigned int* outbits = (unsigned int*)d_out;

    const size_t ff_bytes = (size_t)F * K;       // 24 MB facts fp8
    const size_t qf_bytes = (size_t)B * K;       // 768 KB queries fp8
    const size_t need_full = ff_bytes + qf_bytes + (size_t)F * 4 + (size_t)B * 4;
    const size_t qb_bytes = (size_t)B * K * 2;
    const size_t need_lean = qb_bytes + (size_t)F * 4 + (size_t)B * 4;

    const bool shapes_ok = (B % 256 == 0) && (F % 1024 == 0);
    if (ws_size >= need_full && shapes_ok) {
        unsigned char* Ff = (unsigned char*)d_ws;
        unsigned char* Qf = (unsigned char*)d_ws + ff_bytes;
        float* fsq = (float*)((char*)d_ws + ff_bytes + qf_bytes);
        float* qsq = fsq + F;
        prep_kernel<<<B / 4 + F / 4, 256, 0, stream>>>(rel, a1, a2, fr, fa1, fa2,
                                                       Qf, Ff, qsq, fsq, outbits, B, F);
        // grid: x = n-groups (facts streamed once; R9-verified 15.5MB FETCH),
        // y = m-tiles of 256. 16 tiles of 64 facts per WG, double-buffered.
        gemm_pipe_kernel<<<dim3(F / 1024, B / 256), 256, 0, stream>>>(
            Qf, Ff, qsq, fsq, outbits, 16);
    } else if (ws_size >= need_lean && B % 128 == 0 && F % 128 == 0) {
        unsigned short* Qb = (unsigned short*)d_ws;
        float* fsq = (float*)((char*)d_ws + qb_bytes);
        float* qsq = fsq + F;
        init_min_kernel<<<(B + 255) / 256, 256, 0, stream>>>(outbits, B);
        conv_rows_kernel<<<B / 4, 256, 0, stream>>>(rel, a1, a2, Qb, qsq, B);
        conv_rows_kernel<<<F / 4, 256, 0, stream>>>(fr, fa1, fa2, nullptr, fsq, F);
        gemm_lean_kernel<<<dim3(B / 128, F / 128), 256, 0, stream>>>(
            Qb, fr, fa1, fa2, qsq, fsq, outbits, K);
    } else {
        init_min_kernel<<<(B + 255) / 256, 256, 0, stream>>>(outbits, B);
        tier3_kernel<<<dim3(F / 2048, B / 16), 256, 0, stream>>>(rel, a1, a2, fr, fa1, fa2, outbits);
    }

    finalize_kernel<<<(B + 255) / 256, 256, 0, stream>>>(out, B);
}